// Round 2
// baseline (1095.018 us; speedup 1.0000x reference)
//
#include <hip/hip_runtime.h>
#include <hip/hip_bf16.h>

#define NROIS 333
#define BATCH 512
#define NREG 300
#define NCLS 180
#define EPSV 1e-5f
#define SLOPEV 0.3f

// ---------------- metadata: derive per-ROI {in_off, size, out_off, reduced} ----------------
__global__ void meta_kernel(const int* __restrict__ idx, const int* __restrict__ src,
                            int* __restrict__ meta, int max_in, int max_out,
                            int total, int concat_dim) {
  int r = blockIdx.x * blockDim.x + threadIdx.x;
  if (r >= NROIS) return;
  const int* row = idx + (long)r * max_in;
  int in_off = row[0];
  int size = max_in;
  for (int k = 1; k < max_in; ++k) { if (row[k] == total) { size = k; break; } }
  int t1 = r * max_out;
  int lo = 0, hi = concat_dim;
  while (lo < hi) { int mid = (lo + hi) >> 1; if (src[mid] < t1) lo = mid + 1; else hi = mid; }
  int out_off = lo;
  int t2 = t1 + max_out;
  hi = concat_dim;
  while (lo < hi) { int mid = (lo + hi) >> 1; if (src[mid] < t2) lo = mid + 1; else hi = mid; }
  meta[r] = in_off;
  meta[NROIS + r] = size;
  meta[2 * NROIS + r] = out_off;
  meta[3 * NROIS + r] = lo - out_off;
}

// ---------------- seed reg_out region of d_out with b_reg (d_out is poisoned 0xAA) ----------------
__global__ void init_reg_kernel(const float* __restrict__ b_reg, float* __restrict__ reg_out) {
  int i = blockIdx.x * blockDim.x + threadIdx.x;
  if (i < BATCH * NREG) reg_out[i] = b_reg[i % NREG];
}

// ---------------- encoder: per-ROI GEMM + BN + leaky, scatter into concat ----------------
__global__ __launch_bounds__(256) void enc_kernel(
    const float* __restrict__ x,
    const float* __restrict__ W_enc,
    const float* __restrict__ b_enc,
    const float* __restrict__ gamma,
    const float* __restrict__ beta,
    const float* __restrict__ run_mean,
    const float* __restrict__ run_var,
    const int* __restrict__ meta,
    float* __restrict__ concat_out,
    int total, int max_in, int max_out, int concat_dim) {
  int r = blockIdx.x;
  int b0 = blockIdx.y * 64;
  int in_off  = meta[r];
  int size    = meta[NROIS + r];
  int out_off = meta[2 * NROIS + r];
  int red     = meta[3 * NROIS + r];

  __shared__ float xs[64][33];  // pitch 33: lane-stride reads are free 2-way
  __shared__ float wl[64][36];  // pitch 36: 16B-aligned rows for float4 broadcast reads

  int t = threadIdx.x;
  int bl = t & 63;      // batch lane within tile
  int og = t >> 6;      // output group 0..3

  float acc[16];
  #pragma unroll
  for (int m = 0; m < 16; m++) acc[m] = 0.f;

  int i = t >> 2;            // staged row 0..63
  int g = (t & 3) * 8;       // column group
  const float* xrow = x + (long)(b0 + i) * total + in_off;
  const float* wrow = W_enc + ((long)r * max_out + i) * max_in;

  for (int kb = 0; kb < size; kb += 32) {
    #pragma unroll
    for (int e = 0; e < 8; e++) {
      int j = g + e, k = kb + j;
      xs[i][j] = (k < size) ? xrow[k] : 0.f;
    }
    if (i < red) {
      #pragma unroll
      for (int e = 0; e < 8; e++) {
        int j = g + e, k = kb + j;
        wl[i][j] = (k < size) ? wrow[k] : 0.f;
      }
    }
    __syncthreads();
    #pragma unroll
    for (int j4 = 0; j4 < 32; j4 += 4) {
      float x0 = xs[bl][j4 + 0], x1 = xs[bl][j4 + 1];
      float x2 = xs[bl][j4 + 2], x3 = xs[bl][j4 + 3];
      #pragma unroll
      for (int m = 0; m < 16; m++) {
        int oi = og + 4 * m;
        if (oi < red) {  // wave-uniform (og uniform per wave, red uniform per block)
          const float4 w4 = *(const float4*)&wl[oi][j4];
          acc[m] += x0 * w4.x + x1 * w4.y + x2 * w4.z + x3 * w4.w;
        }
      }
    }
    __syncthreads();
  }

  long base = (long)r * max_out;
  #pragma unroll
  for (int m = 0; m < 16; m++) {
    int oi = og + 4 * m;
    if (oi < red) {
      float z  = acc[m] + b_enc[base + oi];
      float y = gamma[base + oi] * (z - run_mean[base + oi]) * rsqrtf(run_var[base + oi] + EPSV)
              + beta[base + oi];
      y = (y > 0.f) ? y : SLOPEV * y;
      concat_out[(long)(b0 + bl) * concat_dim + out_off + oi] = y;
    }
  }
}

// ---------------- reg GEMM: concat(512 x cd) @ W_reg^T, split-K + fp32 atomics into d_out ----------------
__global__ __launch_bounds__(256) void reg_kernel(
    const float* __restrict__ concat,
    const float* __restrict__ W_reg,
    float* __restrict__ reg_out,
    int concat_dim, int span) {
  int j0 = blockIdx.x * 64;
  int b0 = blockIdx.y * 64;
  int kstart = blockIdx.z * span;
  int kend = min(kstart + span, concat_dim);
  if (kstart >= kend) return;  // uniform exit

  __shared__ float as[64][33];
  __shared__ float bs[64][36];

  int t = threadIdx.x;
  int bl = t & 63, og = t >> 6;
  float acc[16];
  #pragma unroll
  for (int m = 0; m < 16; m++) acc[m] = 0.f;

  int i = t >> 2, g = (t & 3) * 8;
  const float* arow = concat + (long)(b0 + i) * concat_dim;
  int jr = j0 + i;
  bool bvalid = (jr < NREG);
  const float* brow = W_reg + (long)(bvalid ? jr : 0) * concat_dim;

  for (int cb = kstart; cb < kend; cb += 32) {
    #pragma unroll
    for (int e = 0; e < 8; e++) {
      int c = cb + g + e;
      as[i][g + e] = (c < kend) ? arow[c] : 0.f;
      bs[i][g + e] = (bvalid && c < kend) ? brow[c] : 0.f;
    }
    __syncthreads();
    #pragma unroll
    for (int j4 = 0; j4 < 32; j4 += 4) {
      float a0 = as[bl][j4 + 0], a1 = as[bl][j4 + 1];
      float a2 = as[bl][j4 + 2], a3 = as[bl][j4 + 3];
      #pragma unroll
      for (int m = 0; m < 16; m++) {
        const float4 w4 = *(const float4*)&bs[og + 4 * m][j4];
        acc[m] += a0 * w4.x + a1 * w4.y + a2 * w4.z + a3 * w4.w;
      }
    }
    __syncthreads();
  }
  #pragma unroll
  for (int m = 0; m < 16; m++) {
    int j = j0 + og + 4 * m;
    if (j < NREG) atomicAdd(&reg_out[(long)(b0 + bl) * NREG + j], acc[m]);
  }
}

// ---------------- cls: read reg_out, 180-wide GEMV, softmax ----------------
__global__ __launch_bounds__(192) void cls_kernel(
    const float* __restrict__ reg_out,
    const float* __restrict__ W_cls,
    const float* __restrict__ b_cls,
    float* __restrict__ cls_out) {
  int b = blockIdx.x;
  int t = threadIdx.x;
  __shared__ float rrow[NREG];
  __shared__ float lm[3];
  for (int iB = t; iB < NREG; iB += 192) rrow[iB] = reg_out[(long)b * NREG + iB];
  __syncthreads();
  float s = 0.f;
  if (t < NCLS) {
    s = b_cls[t];
    const float* wr = W_cls + (long)t * NREG;
    for (int iB = 0; iB < NREG; ++iB) s += rrow[iB] * wr[iB];
  }
  float v = (t < NCLS) ? s : -3.4e38f;
  #pragma unroll
  for (int o = 32; o > 0; o >>= 1) v = fmaxf(v, __shfl_xor(v, o, 64));
  if ((t & 63) == 0) lm[t >> 6] = v;
  __syncthreads();
  float bmax = fmaxf(fmaxf(lm[0], lm[1]), lm[2]);
  __syncthreads();
  float e = (t < NCLS) ? __expf(s - bmax) : 0.f;
  float ss = e;
  #pragma unroll
  for (int o = 32; o > 0; o >>= 1) ss += __shfl_xor(ss, o, 64);
  if ((t & 63) == 0) lm[t >> 6] = ss;
  __syncthreads();
  float bsum = lm[0] + lm[1] + lm[2];
  if (t < NCLS) cls_out[(long)b * NCLS + t] = e / bsum;
}

extern "C" void kernel_launch(void* const* d_in, const int* in_sizes, int n_in,
                              void* d_out, int out_size, void* d_ws, size_t ws_size,
                              hipStream_t stream) {
  const float* x     = (const float*)d_in[0];
  const float* W_enc = (const float*)d_in[1];
  const float* b_enc = (const float*)d_in[2];
  const float* gam   = (const float*)d_in[3];
  const float* bet   = (const float*)d_in[4];
  const float* rmean = (const float*)d_in[5];
  const float* rvar  = (const float*)d_in[6];
  const float* W_reg = (const float*)d_in[7];
  const float* b_reg = (const float*)d_in[8];
  const float* W_cls = (const float*)d_in[9];
  const float* b_cls = (const float*)d_in[10];
  const int* idx = (const int*)d_in[11];
  const int* src = (const int*)d_in[12];

  int total      = in_sizes[0] / BATCH;
  int max_out    = in_sizes[2] / NROIS;
  int max_in     = in_sizes[11] / NROIS;
  int concat_dim = in_sizes[12];

  int* meta = (int*)d_ws;  // 4*NROIS ints = 5.3 KB

  float* out_concat = (float*)d_out;
  float* out_reg = out_concat + (long)BATCH * concat_dim;
  float* out_cls = out_reg + (long)BATCH * NREG;

  meta_kernel<<<dim3((NROIS + 255) / 256), 256, 0, stream>>>(idx, src, meta, max_in, max_out, total, concat_dim);
  init_reg_kernel<<<dim3((BATCH * NREG + 255) / 256), 256, 0, stream>>>(b_reg, out_reg);
  enc_kernel<<<dim3(NROIS, BATCH / 64), 256, 0, stream>>>(x, W_enc, b_enc, gam, bet, rmean, rvar,
                                                          meta, out_concat, total, max_in, max_out, concat_dim);
  const int SPLIT = 16;
  int span = ((concat_dim + SPLIT * 32 - 1) / (SPLIT * 32)) * 32;
  reg_kernel<<<dim3((NREG + 63) / 64, BATCH / 64, SPLIT), 256, 0, stream>>>(out_concat, W_reg, out_reg, concat_dim, span);
  cls_kernel<<<BATCH, 192, 0, stream>>>(out_reg, W_cls, b_cls, out_cls);
}

// Round 3
// 606.769 us; speedup vs baseline: 1.8047x; 1.8047x over previous
//
#include <hip/hip_runtime.h>
#include <hip/hip_bf16.h>

#define NROIS 333
#define BATCH 512
#define NREG 300
#define NCLS 180
#define EPSV 1e-5f
#define SLOPEV 0.3f

typedef __attribute__((ext_vector_type(8))) short bf16x8;
typedef __attribute__((ext_vector_type(4))) float f32x4;

// ---------------- metadata: derive per-ROI {in_off, size, out_off, reduced} ----------------
__global__ void meta_kernel(const int* __restrict__ idx, const int* __restrict__ src,
                            int* __restrict__ meta, int max_in, int max_out,
                            int total, int concat_dim) {
  int r = blockIdx.x * blockDim.x + threadIdx.x;
  if (r >= NROIS) return;
  const int* row = idx + (long)r * max_in;
  int in_off = row[0];
  int size = max_in;
  for (int k = 1; k < max_in; ++k) { if (row[k] == total) { size = k; break; } }
  int t1 = r * max_out;
  int lo = 0, hi = concat_dim;
  while (lo < hi) { int mid = (lo + hi) >> 1; if (src[mid] < t1) lo = mid + 1; else hi = mid; }
  int out_off = lo;
  int t2 = t1 + max_out;
  hi = concat_dim;
  while (lo < hi) { int mid = (lo + hi) >> 1; if (src[mid] < t2) lo = mid + 1; else hi = mid; }
  meta[r] = in_off;
  meta[NROIS + r] = size;
  meta[2 * NROIS + r] = out_off;
  meta[3 * NROIS + r] = lo - out_off;
}

// ---------------- seed reg_out region of d_out with b_reg (d_out poisoned 0xAA) ----------------
__global__ void init_reg_kernel(const float* __restrict__ b_reg, float* __restrict__ reg_out) {
  int i = blockIdx.x * blockDim.x + threadIdx.x;
  if (i < BATCH * NREG) reg_out[i] = b_reg[i % NREG];
}

// ---------------- encoder: per-ROI MFMA GEMM + BN + leaky, scatter into concat ----------------
__global__ __launch_bounds__(256) void enc_kernel(
    const float* __restrict__ x,
    const float* __restrict__ W_enc,
    const float* __restrict__ b_enc,
    const float* __restrict__ gamma,
    const float* __restrict__ beta,
    const float* __restrict__ run_mean,
    const float* __restrict__ run_var,
    const int* __restrict__ meta,
    float* __restrict__ concat_out,
    int total, int max_in, int max_out, int concat_dim) {
  int r = blockIdx.x;
  int b0 = blockIdx.y * 64;
  int in_off  = meta[r];
  int size    = meta[NROIS + r];
  int out_off = meta[2 * NROIS + r];
  int red     = meta[3 * NROIS + r];
  int ntiles  = (red + 15) >> 4;   // 1..4, block-uniform

  // fragment-chunk layout: [k-quad][row][8 bf16] -> each lane frag = one ds_read_b128
  __shared__ __hip_bfloat16 gs[4][64][8];
  __shared__ __hip_bfloat16 wsh[4][64][8];

  int t = threadIdx.x;
  int rr = t >> 2;          // staged row 0..63
  int q  = t & 3;           // k-chunk of 8
  const float* xrow = x + (long)(b0 + rr) * total + in_off;
  const float* wrow = W_enc + ((long)r * max_out + rr) * max_in;
  bool wvalid = rr < red;

  int w  = t >> 6;          // wave id: batch rows 16w..16w+15
  int l  = t & 63;
  int lq = l >> 4, lm = l & 15;

  f32x4 acc[4];
  #pragma unroll
  for (int nb = 0; nb < 4; nb++) acc[nb] = (f32x4){0.f, 0.f, 0.f, 0.f};

  const __hip_bfloat16 bz = __float2bfloat16(0.f);

  for (int kb = 0; kb < size; kb += 32) {
    int k0 = kb + q * 8;
    union { bf16x8 v; __hip_bfloat16 h[8]; } gv, wv;
    if (k0 + 8 <= size) {
      float4 a0 = *(const float4*)(xrow + k0);
      float4 a1 = *(const float4*)(xrow + k0 + 4);
      gv.h[0] = __float2bfloat16(a0.x); gv.h[1] = __float2bfloat16(a0.y);
      gv.h[2] = __float2bfloat16(a0.z); gv.h[3] = __float2bfloat16(a0.w);
      gv.h[4] = __float2bfloat16(a1.x); gv.h[5] = __float2bfloat16(a1.y);
      gv.h[6] = __float2bfloat16(a1.z); gv.h[7] = __float2bfloat16(a1.w);
      if (wvalid) {
        float4 c0 = *(const float4*)(wrow + k0);
        float4 c1 = *(const float4*)(wrow + k0 + 4);
        wv.h[0] = __float2bfloat16(c0.x); wv.h[1] = __float2bfloat16(c0.y);
        wv.h[2] = __float2bfloat16(c0.z); wv.h[3] = __float2bfloat16(c0.w);
        wv.h[4] = __float2bfloat16(c1.x); wv.h[5] = __float2bfloat16(c1.y);
        wv.h[6] = __float2bfloat16(c1.z); wv.h[7] = __float2bfloat16(c1.w);
      } else {
        #pragma unroll
        for (int e = 0; e < 8; e++) wv.h[e] = bz;
      }
    } else {
      #pragma unroll
      for (int e = 0; e < 8; e++) {
        int k = k0 + e;
        gv.h[e] = (k < size) ? __float2bfloat16(xrow[k]) : bz;
        wv.h[e] = (wvalid && k < size) ? __float2bfloat16(wrow[k]) : bz;
      }
    }
    *(bf16x8*)&gs[q][rr][0]  = gv.v;
    *(bf16x8*)&wsh[q][rr][0] = wv.v;
    __syncthreads();

    bf16x8 af = *(const bf16x8*)&gs[lq][16 * w + lm][0];
    for (int nb = 0; nb < ntiles; nb++) {   // block-uniform trip count
      bf16x8 bfrag = *(const bf16x8*)&wsh[lq][nb * 16 + lm][0];
      acc[nb] = __builtin_amdgcn_mfma_f32_16x16x32_bf16(af, bfrag, acc[nb], 0, 0, 0);
    }
    __syncthreads();
  }

  long base = (long)r * max_out;
  for (int nb = 0; nb < ntiles; nb++) {
    int oc = nb * 16 + lm;                  // C/D col = lane&15
    if (oc < red) {
      float be = b_enc[base + oc];
      float sc = gamma[base + oc] * rsqrtf(run_var[base + oc] + EPSV);
      float mu = run_mean[base + oc];
      float bt = beta[base + oc];
      #pragma unroll
      for (int i = 0; i < 4; i++) {         // C/D row = quad*4 + reg
        int br = b0 + 16 * w + lq * 4 + i;
        float y = sc * (acc[nb][i] + be - mu) + bt;
        y = (y > 0.f) ? y : SLOPEV * y;
        concat_out[(long)br * concat_dim + out_off + oc] = y;
      }
    }
  }
}

// ---------------- reg GEMM: concat(512 x cd) @ W_reg^T, MFMA + split-K atomics into d_out ----------------
__global__ __launch_bounds__(256) void reg_kernel(
    const float* __restrict__ concat,
    const float* __restrict__ W_reg,
    float* __restrict__ reg_out,
    int concat_dim, int span) {
  int j0 = blockIdx.x * 64;
  int b0 = blockIdx.y * 64;
  int kstart = blockIdx.z * span;
  int kend = min(kstart + span, concat_dim);
  if (kstart >= kend) return;               // uniform exit
  int ntiles = min(4, (NREG - j0 + 15) >> 4);

  __shared__ __hip_bfloat16 as_[4][64][8];
  __shared__ __hip_bfloat16 bs_[4][64][8];

  int t = threadIdx.x;
  int rr = t >> 2, q = t & 3;
  const float* arow = concat + (long)(b0 + rr) * concat_dim;
  int jr = j0 + rr;
  bool bvalid = jr < NREG;
  const float* brow = W_reg + (long)(bvalid ? jr : 0) * concat_dim;

  int w = t >> 6, l = t & 63, lq = l >> 4, lm = l & 15;
  f32x4 acc[4];
  #pragma unroll
  for (int nb = 0; nb < 4; nb++) acc[nb] = (f32x4){0.f, 0.f, 0.f, 0.f};
  const __hip_bfloat16 bz = __float2bfloat16(0.f);

  for (int kb = kstart; kb < kend; kb += 32) {
    int k0 = kb + q * 8;
    union { bf16x8 v; __hip_bfloat16 h[8]; } av, bv;
    if (k0 + 8 <= kend) {
      float4 a0 = *(const float4*)(arow + k0);
      float4 a1 = *(const float4*)(arow + k0 + 4);
      av.h[0] = __float2bfloat16(a0.x); av.h[1] = __float2bfloat16(a0.y);
      av.h[2] = __float2bfloat16(a0.z); av.h[3] = __float2bfloat16(a0.w);
      av.h[4] = __float2bfloat16(a1.x); av.h[5] = __float2bfloat16(a1.y);
      av.h[6] = __float2bfloat16(a1.z); av.h[7] = __float2bfloat16(a1.w);
      if (bvalid) {
        float4 c0 = *(const float4*)(brow + k0);
        float4 c1 = *(const float4*)(brow + k0 + 4);
        bv.h[0] = __float2bfloat16(c0.x); bv.h[1] = __float2bfloat16(c0.y);
        bv.h[2] = __float2bfloat16(c0.z); bv.h[3] = __float2bfloat16(c0.w);
        bv.h[4] = __float2bfloat16(c1.x); bv.h[5] = __float2bfloat16(c1.y);
        bv.h[6] = __float2bfloat16(c1.z); bv.h[7] = __float2bfloat16(c1.w);
      } else {
        #pragma unroll
        for (int e = 0; e < 8; e++) bv.h[e] = bz;
      }
    } else {
      #pragma unroll
      for (int e = 0; e < 8; e++) {
        int k = k0 + e;
        av.h[e] = (k < kend) ? __float2bfloat16(arow[k]) : bz;
        bv.h[e] = (bvalid && k < kend) ? __float2bfloat16(brow[k]) : bz;
      }
    }
    *(bf16x8*)&as_[q][rr][0] = av.v;
    *(bf16x8*)&bs_[q][rr][0] = bv.v;
    __syncthreads();

    bf16x8 af = *(const bf16x8*)&as_[lq][16 * w + lm][0];
    for (int nb = 0; nb < ntiles; nb++) {
      bf16x8 bfrag = *(const bf16x8*)&bs_[lq][nb * 16 + lm][0];
      acc[nb] = __builtin_amdgcn_mfma_f32_16x16x32_bf16(af, bfrag, acc[nb], 0, 0, 0);
    }
    __syncthreads();
  }

  for (int nb = 0; nb < ntiles; nb++) {
    int j = j0 + nb * 16 + lm;
    if (j < NREG) {
      #pragma unroll
      for (int i = 0; i < 4; i++) {
        int br = b0 + 16 * w + lq * 4 + i;
        atomicAdd(&reg_out[(long)br * NREG + j], acc[nb][i]);
      }
    }
  }
}

// ---------------- cls: read reg_out, 180-wide GEMV (float4), softmax ----------------
__global__ __launch_bounds__(192) void cls_kernel(
    const float* __restrict__ reg_out,
    const float* __restrict__ W_cls,
    const float* __restrict__ b_cls,
    float* __restrict__ cls_out) {
  int b = blockIdx.x;
  int t = threadIdx.x;
  __shared__ __align__(16) float rrow[NREG];
  __shared__ float lm[3];
  for (int iB = t; iB < NREG; iB += 192) rrow[iB] = reg_out[(long)b * NREG + iB];
  __syncthreads();
  float s = 0.f;
  if (t < NCLS) {
    s = b_cls[t];
    const float4* wr  = (const float4*)(W_cls + (long)t * NREG);
    const float4* rr4 = (const float4*)rrow;
    #pragma unroll 5
    for (int i = 0; i < NREG / 4; ++i) {
      float4 wv = wr[i], rv = rr4[i];
      s += wv.x * rv.x + wv.y * rv.y + wv.z * rv.z + wv.w * rv.w;
    }
  }
  float v = (t < NCLS) ? s : -3.4e38f;
  #pragma unroll
  for (int o = 32; o > 0; o >>= 1) v = fmaxf(v, __shfl_xor(v, o, 64));
  if ((t & 63) == 0) lm[t >> 6] = v;
  __syncthreads();
  float bmax = fmaxf(fmaxf(lm[0], lm[1]), lm[2]);
  __syncthreads();
  float e = (t < NCLS) ? __expf(s - bmax) : 0.f;
  float ss = e;
  #pragma unroll
  for (int o = 32; o > 0; o >>= 1) ss += __shfl_xor(ss, o, 64);
  if ((t & 63) == 0) lm[t >> 6] = ss;
  __syncthreads();
  float bsum = lm[0] + lm[1] + lm[2];
  if (t < NCLS) cls_out[(long)b * NCLS + t] = e / bsum;
}

extern "C" void kernel_launch(void* const* d_in, const int* in_sizes, int n_in,
                              void* d_out, int out_size, void* d_ws, size_t ws_size,
                              hipStream_t stream) {
  const float* x     = (const float*)d_in[0];
  const float* W_enc = (const float*)d_in[1];
  const float* b_enc = (const float*)d_in[2];
  const float* gam   = (const float*)d_in[3];
  const float* bet   = (const float*)d_in[4];
  const float* rmean = (const float*)d_in[5];
  const float* rvar  = (const float*)d_in[6];
  const float* W_reg = (const float*)d_in[7];
  const float* b_reg = (const float*)d_in[8];
  const float* W_cls = (const float*)d_in[9];
  const float* b_cls = (const float*)d_in[10];
  const int* idx = (const int*)d_in[11];
  const int* src = (const int*)d_in[12];

  int total      = in_sizes[0] / BATCH;
  int max_out    = in_sizes[2] / NROIS;
  int max_in     = in_sizes[11] / NROIS;
  int concat_dim = in_sizes[12];

  int* meta = (int*)d_ws;  // 4*NROIS ints

  float* out_concat = (float*)d_out;
  float* out_reg = out_concat + (long)BATCH * concat_dim;
  float* out_cls = out_reg + (long)BATCH * NREG;

  meta_kernel<<<dim3((NROIS + 255) / 256), 256, 0, stream>>>(idx, src, meta, max_in, max_out, total, concat_dim);
  init_reg_kernel<<<dim3((BATCH * NREG + 255) / 256), 256, 0, stream>>>(b_reg, out_reg);
  enc_kernel<<<dim3(NROIS, BATCH / 64), 256, 0, stream>>>(x, W_enc, b_enc, gam, bet, rmean, rvar,
                                                          meta, out_concat, total, max_in, max_out, concat_dim);
  const int SPLIT = 8;
  int span = ((concat_dim + SPLIT * 32 - 1) / (SPLIT * 32)) * 32;
  reg_kernel<<<dim3((NREG + 63) / 64, BATCH / 64, SPLIT), 256, 0, stream>>>(out_concat, W_reg, out_reg, concat_dim, span);
  cls_kernel<<<BATCH, 192, 0, stream>>>(out_reg, W_cls, b_cls, out_cls);
}